// Round 6
// baseline (564.816 us; speedup 1.0000x reference)
//
#include <hip/hip_runtime.h>
#include <hip/hip_cooperative_groups.h>
#include <stdint.h>

namespace cg = cooperative_groups;

#define NBATCH 16
#define HW_ (1 << 20)            // 1024*1024 per batch
#define NB 512                   // grid blocks; co-resident: 2 blocks/CU x 256 CU
#define TPBC 512                 // threads per block (8 waves)
#define NBPB 32                  // blocks per batch
#define EPB (HW_ / NBPB)         // 32768 elems per block in heavy phases
#define ITER_P (EPB / (TPBC * 4))// 16 float4 per thread

#define NBINS 8192               // fine bins on score_bits >> 12; base 0x3F400
#define FBASE 0x3F400
#define NSLICE 32                // bin slices per batch in reduce phase
#define SLICE_BINS 256           // bins per slice

#define CAND_CAP 32768
#define LCAP 512
#define TIE_CAP 4096
#define CNT_STRIDE 64

#define BUF_W 10242              // 41 KB shared union

typedef float f4v __attribute__((ext_vector_type(4)));

struct BParams {
    unsigned int k;
    unsigned int bin1f;
    unsigned int r;
    unsigned int mode;
};

__device__ __forceinline__ unsigned int score_bits(float p, int m) {
    bool correct = (p > 0.5f) == (m == 1);
    float conf = fmaxf(p, 1.0f - p);
    float base = correct ? ((conf > 0.85f) ? 1.0f : 2.0f)
                         : ((conf > 0.85f) ? 4.0f : 3.0f);
    float bonus = (conf - 0.5f) * 0.5f;   // exact in f32
    float s = correct ? (base - bonus) : (base + bonus);
    return __float_as_uint(s);            // positive floats: bit order == value order
}

__global__ __launch_bounds__(TPBC, 4) void k_all(
    const float4* __restrict__ pred4, const int4* __restrict__ mask4,
    float* __restrict__ out,
    unsigned int* __restrict__ cand_cnt, BParams* __restrict__ prm,
    float* __restrict__ partials, float* __restrict__ tie_partials,
    unsigned int* __restrict__ cand_idx, unsigned int* __restrict__ cand_sb,
    float* __restrict__ cand_bce, unsigned int* __restrict__ hist1,
    unsigned int* __restrict__ stot, unsigned int* __restrict__ hist_part16)
{
    cg::grid_group grid = cg::this_grid();
    __shared__ __align__(16) unsigned int buf[BUF_W];
    const int blk = blockIdx.x;
    const int t = threadIdx.x;
    const int b = blk / NBPB;
    const int sb = blk % NBPB;
    const int lane = t & 63;

    // ================= Phase A: per-block 8192-bin LDS histogram =================
    for (int i = t; i < NBINS; i += TPBC) buf[i] = 0;
    if (blk == 0)
        for (int i = t; i < NBATCH * CNT_STRIDE; i += TPBC) cand_cnt[i] = 0;
    __syncthreads();
    {
        size_t gb = (size_t)b * (HW_ / 4) + (size_t)sb * (EPB / 4);
        float4 p = pred4[gb + t];
        int4 m = mask4[gb + t];
        for (int j = 0; j < ITER_P; j++) {
            float4 pc = p; int4 mc = m;
            if (j + 1 < ITER_P) {
                p = pred4[gb + (size_t)(j + 1) * TPBC + t];
                m = mask4[gb + (size_t)(j + 1) * TPBC + t];
            }
            float pa[4] = {pc.x, pc.y, pc.z, pc.w};
            int   ma[4] = {mc.x, mc.y, mc.z, mc.w};
#pragma unroll
            for (int l = 0; l < 4; l++) {
                if (ma[l] != 2) {
                    unsigned int sbit = score_bits(pa[l], ma[l]);
                    int fb = (int)(sbit >> 12) - FBASE;
                    fb = min(max(fb, 0), NBINS - 1);
                    atomicAdd(&buf[fb], 1u);
                }
            }
        }
    }
    __syncthreads();
    {
        unsigned int* hp = hist_part16 + (size_t)blk * (NBINS / 2);
        for (int w = t; w < NBINS / 2; w += TPBC)
            hp[w] = (buf[2 * w] & 0xFFFFu) | (buf[2 * w + 1] << 16);
    }
    grid.sync();

    // ===== Phase B1: 32 blocks/batch each sum one 256-bin slice over 32 partials =====
    if (t < 128) {
        unsigned int s0 = 0, s1 = 0;
        for (int p = 0; p < NBPB; p++) {
            unsigned int w = hist_part16[(size_t)(b * NBPB + p) * (NBINS / 2) + sb * 128 + t];
            s0 += w & 0xFFFFu; s1 += w >> 16;
        }
        hist1[(size_t)b * NBINS + sb * SLICE_BINS + 2 * t] = s0;
        hist1[(size_t)b * NBINS + sb * SLICE_BINS + 2 * t + 1] = s1;
        buf[t] = s0 + s1;
    }
    __syncthreads();
    for (int off = 64; off > 0; off >>= 1) {
        if (t < off) buf[t] += buf[t + off];
        __syncthreads();
    }
    if (t == 0) stot[b * NBPB + sb] = buf[0];
    grid.sync();

    // ===== Phase B2: one block/batch picks the k-th-largest fine bin =====
    if (sb == 0) {
        if (t < NSLICE) buf[256 + t] = stot[b * NBPB + t];
        __syncthreads();
        if (t == 0) {
            unsigned int run = 0;
            for (int i = NSLICE - 1; i >= 0; i--) { run += buf[256 + i]; buf[288 + i] = run; }
            buf[320] = run;
        }
        __syncthreads();
        unsigned int n = buf[320];
        unsigned int k = (unsigned int)(int)((float)n * 0.5f);  // astype(f32)*0.5 -> int32
        if (k == 0) {
            if (t == 0) { BParams P; P.k = 0; P.bin1f = 0xFFFFFFFFu; P.r = 0; P.mode = 0; prm[b] = P; }
        } else {
            if (t == 0) {
                int ss = 0;
                for (int i = NSLICE - 1; i >= 0; i--) {
                    unsigned int sufi = buf[288 + i];
                    unsigned int sufn = (i == NSLICE - 1) ? 0u : buf[288 + i + 1];
                    if (sufi >= k && sufn < k) { ss = i; break; }
                }
                buf[321] = (unsigned int)ss;
                buf[322] = k - ((ss == NSLICE - 1) ? 0u : buf[288 + ss + 1]);
            }
            __syncthreads();
            unsigned int ss = buf[321], rs = buf[322];
            if (t < SLICE_BINS) buf[512 + t] = hist1[(size_t)b * NBINS + ss * SLICE_BINS + t];
            if (t == 0) buf[512 + SLICE_BINS] = 0;
            __syncthreads();
            for (int off = 1; off < SLICE_BINS; off <<= 1) {
                unsigned int a = (t < SLICE_BINS && t + off < SLICE_BINS) ? buf[512 + t + off] : 0u;
                __syncthreads();
                if (t < SLICE_BINS) buf[512 + t] += a;
                __syncthreads();
            }
            if (t < SLICE_BINS && buf[512 + t] >= rs && buf[512 + t + 1] < rs) {
                BParams P; P.k = k;
                P.bin1f = (unsigned int)(FBASE + ss * SLICE_BINS + t);
                P.r = rs - buf[512 + t + 1];
                P.mode = 1;
                prm[b] = P;
            }
        }
    }
    grid.sync();

    // ================= Phase C: main fused pass (32768 elems/block) =================
    {
        unsigned int* lcode = buf;                   // [8192]
        unsigned int* l_idx = buf + 8192;            // [512]
        unsigned int* l_sbv = buf + 8704;            // [512]
        float*        l_bce = (float*)(buf + 9216);  // [512]
        float*        redf  = (float*)(buf + 9728);  // [512]
        BParams P = prm[b];
        unsigned int target = P.bin1f;
        if (t == 0) buf[10240] = 0;   // lcnt
        __syncthreads();
        float acc = 0.0f;
        int ibase = sb * EPB;
        size_t base4 = (size_t)b * (HW_ / 4) + (size_t)(ibase / 4);
        float* trout = out + 1;
        float* hoout = out + 1 + (size_t)NBATCH * HW_;
        size_t Gbase = (size_t)b * HW_ + (size_t)ibase;
        float4 p = pred4[base4 + t];
        int4 m = mask4[base4 + t];
        for (int j = 0; j < ITER_P; j++) {
            int v = j * TPBC + t;
            float4 pc = p; int4 mc = m;
            if (j + 1 < ITER_P) {
                p = pred4[base4 + (size_t)(j + 1) * TPBC + t];
                m = mask4[base4 + (size_t)(j + 1) * TPBC + t];
            }
            float pa[4] = {pc.x, pc.y, pc.z, pc.w};
            int   ma[4] = {mc.x, mc.y, mc.z, mc.w};
            unsigned int cw = 0;
#pragma unroll
            for (int l = 0; l < 4; l++) {
                bool ann = (ma[l] != 2);
                unsigned int sbit = score_bits(pa[l], ma[l]);
                unsigned int fine = sbit >> 12;
                bool tr = ann && (fine > target);
                bool amb = ann && (fine == target);
                unsigned int code = (tr ? 1u : 0u) | ((ann && !tr) ? 2u : 0u);
                cw |= code << (8 * l);
                float bce = 0.0f;
                if (tr || amb) {
                    float pc2 = fminf(fmaxf(pa[l], 1e-7f), 1.0f - 1e-7f);
                    bce = (ma[l] == 1) ? -__logf(pc2) : -__logf(1.0f - pc2);
                }
                if (tr) acc += bce;
                if (amb) {
                    unsigned int p0 = atomicAdd(&buf[10240], 1u);
                    if (p0 < LCAP) {
                        l_idx[p0] = (unsigned int)(ibase + v * 4 + l);
                        l_sbv[p0] = sbit;
                        l_bce[p0] = bce;
                    } else {
                        unsigned int gp = atomicAdd(&cand_cnt[b * CNT_STRIDE], 1u);
                        if (gp < CAND_CAP) {
                            size_t o = (size_t)b * CAND_CAP + gp;
                            cand_idx[o] = (unsigned int)(ibase + v * 4 + l);
                            cand_sb[o] = sbit;
                            cand_bce[o] = bce;
                        }
                    }
                }
            }
            lcode[v] = cw;
            unsigned int nw = (unsigned int)__shfl_down((int)cw, 1);
            if (lane != 63) {
                unsigned int c0 = cw >> 24;
                unsigned int c1 = nw & 0xFFu;
                unsigned int c2 = (nw >> 8) & 0xFFu;
                unsigned int c3 = (nw >> 16) & 0xFFu;
                int e = 3 + 4 * v;
                f4v tv = { (float)(c0 & 1u), (float)(c1 & 1u), (float)(c2 & 1u), (float)(c3 & 1u) };
                f4v hv = { (float)((c0 >> 1) & 1u), (float)((c1 >> 1) & 1u),
                           (float)((c2 >> 1) & 1u), (float)((c3 >> 1) & 1u) };
                *(f4v*)(trout + Gbase + e) = tv;
                *(f4v*)(hoout + Gbase + e) = hv;
            }
        }
        __syncthreads();
        unsigned int ncand = min(buf[10240], (unsigned int)LCAP);
        if (t == 0 && ncand > 0) buf[10241] = atomicAdd(&cand_cnt[b * CNT_STRIDE], ncand);
        __syncthreads();
        for (unsigned int i = t; i < ncand; i += TPBC) {
            unsigned int pos = buf[10241] + i;
            if (pos < CAND_CAP) {
                size_t o = (size_t)b * CAND_CAP + pos;
                cand_idx[o] = l_idx[i];
                cand_sb[o] = l_sbv[i];
                cand_bce[o] = l_bce[i];
            }
        }
        if (t < 127) {   // wave-boundary words v = 64w+63 (skipped in-loop)
            int v = t * 64 + 63;
            unsigned int w0 = lcode[v];
            unsigned int w1 = lcode[v + 1];
            unsigned int c0 = w0 >> 24;
            unsigned int c1 = w1 & 0xFFu;
            unsigned int c2 = (w1 >> 8) & 0xFFu;
            unsigned int c3 = (w1 >> 16) & 0xFFu;
            int e = 3 + 4 * v;
            f4v tv = { (float)(c0 & 1u), (float)(c1 & 1u), (float)(c2 & 1u), (float)(c3 & 1u) };
            f4v hv = { (float)((c0 >> 1) & 1u), (float)((c1 >> 1) & 1u),
                       (float)((c2 >> 1) & 1u), (float)((c3 >> 1) & 1u) };
            *(f4v*)(trout + Gbase + e) = tv;
            *(f4v*)(hoout + Gbase + e) = hv;
        }
        if (t >= 128 && t < 131) {   // head elems 0,1,2
            int i = t - 128;
            unsigned int c = (lcode[0] >> (8 * i)) & 0xFFu;
            trout[Gbase + i] = (float)(c & 1u);
            hoout[Gbase + i] = (float)((c >> 1) & 1u);
        }
        if (t == 131) {              // tail elem EPB-1
            unsigned int c = (lcode[EPB / 4 - 1] >> 24) & 0xFFu;
            trout[Gbase + EPB - 1] = (float)(c & 1u);
            hoout[Gbase + EPB - 1] = (float)((c >> 1) & 1u);
        }
        redf[t] = acc;
        __syncthreads();
        for (int off = TPBC / 2; off > 0; off >>= 1) {
            if (t < off) redf[t] += redf[t + off];
            __syncthreads();
        }
        if (t == 0) partials[blk] = redf[0];
    }
    grid.sync();

    // ================= Phase D: fixup (one block per batch) =================
    if (sb == 0) {
        unsigned int* h    = buf;                // 4096
        unsigned int* csx  = buf + 4096;         // 513
        unsigned int* tie  = buf + 4609;         // 4096
        unsigned int* misc = buf + 8705;         // 8
        float* redf = (float*)(buf + 8713);      // 512
        BParams P = prm[b];
        if (P.mode == 0) {
            if (t == 0) tie_partials[b] = 0.0f;
        } else {
            unsigned int C = cand_cnt[b * CNT_STRIDE];
            if (C > CAND_CAP) C = CAND_CAP;
            const unsigned int* ci = cand_idx + (size_t)b * CAND_CAP;
            const unsigned int* cs = cand_sb + (size_t)b * CAND_CAP;
            const float* cb = cand_bce + (size_t)b * CAND_CAP;
            for (int i = t; i < 4096; i += TPBC) h[i] = 0;
            if (t < 8) misc[t] = (t == 4) ? 0xFFFFFFFFu : 0u;
            __syncthreads();
            for (unsigned int i = t; i < C; i += TPBC)
                atomicAdd(&h[cs[i] & 0xFFFu], 1u);
            __syncthreads();
            {
                unsigned int gs = 0;
#pragma unroll
                for (int j = 0; j < 8; j++) gs += h[t * 8 + j];
                csx[t] = gs;
                if (t == 0) csx[TPBC] = 0;
            }
            __syncthreads();
            for (int off = 1; off < TPBC; off <<= 1) {
                unsigned int a = (t + off < TPBC) ? csx[t + off] : 0u;
                __syncthreads();
                csx[t] += a;
                __syncthreads();
            }
            if (csx[t] >= P.r && csx[t + 1] < P.r) {
                unsigned int cum = csx[t + 1];
                for (int j = 7; j >= 0; j--) {
                    unsigned int hb = h[t * 8 + j];
                    if (cum + hb >= P.r) {
                        unsigned int T = P.r - cum;
                        misc[0] = (unsigned int)(t * 8 + j);
                        misc[1] = T;
                        misc[2] = (T == hb) ? 1u : 0u;
                        break;
                    }
                    cum += hb;
                }
            }
            __syncthreads();
            unsigned int vstar = misc[0], T = misc[1];
            bool allTies = (misc[2] != 0);
            unsigned int idxcut;
            if (allTies) {
                idxcut = 0xFFFFFFFFu;
            } else {
                for (unsigned int i = t; i < C; i += TPBC) {
                    if ((cs[i] & 0xFFFu) == vstar) {
                        unsigned int p0 = atomicAdd(&misc[3], 1u);
                        if (p0 < TIE_CAP) tie[p0] = ci[i];
                    }
                }
                __syncthreads();
                unsigned int E2 = misc[3];
                if (E2 > TIE_CAP) E2 = TIE_CAP;
                for (unsigned int i = t; i < E2; i += TPBC) {
                    unsigned int vi = tie[i];
                    unsigned int cnt = 0;
                    for (unsigned int j2 = 0; j2 < E2; j2++) cnt += (tie[j2] < vi) ? 1u : 0u;
                    if (cnt == T - 1) misc[4] = vi;
                }
                __syncthreads();
                idxcut = misc[4];
            }
            float accd = 0.0f;
            float* trout = out + 1;
            float* hoout = out + 1 + (size_t)NBATCH * HW_;
            size_t baseo = (size_t)b * HW_;
            for (unsigned int i = t; i < C; i += TPBC) {
                unsigned int low = cs[i] & 0xFFFu;
                bool tr = (low > vstar) || (low == vstar && ci[i] <= idxcut);
                if (tr) {
                    trout[baseo + ci[i]] = 1.0f;
                    hoout[baseo + ci[i]] = 0.0f;
                    accd += cb[i];
                }
            }
            redf[t] = accd;
            __syncthreads();
            for (int off = TPBC / 2; off > 0; off >>= 1) {
                if (t < off) redf[t] += redf[t + off];
                __syncthreads();
            }
            if (t == 0) tie_partials[b] = redf[0];
        }
    }
    grid.sync();

    // ================= Phase E: final loss (block 0) =================
    if (blk == 0) {
        double* redd = (double*)buf;
        double s = (double)partials[t];
        if (t < NBATCH) s += (double)tie_partials[t];
        redd[t] = s;
        __syncthreads();
        for (int off = TPBC / 2; off > 0; off >>= 1) {
            if (t < off) redd[t] += redd[t + off];
            __syncthreads();
        }
        if (t == 0) {
            unsigned long long den = 0;
            for (int b2 = 0; b2 < NBATCH; b2++) den += prm[b2].k;
            out[0] = (float)redd[0] / ((float)den + 1e-7f);
        }
    }
}

extern "C" void kernel_launch(void* const* d_in, const int* in_sizes, int n_in,
                              void* d_out, int out_size, void* d_ws, size_t ws_size,
                              hipStream_t stream) {
    const float4* pred4 = (const float4*)d_in[0];
    const int4* mask4 = (const int4*)d_in[1];
    float* out = (float*)d_out;

    // workspace layout (u32 words); cand_cnt zeroed in-kernel (phase A)
    unsigned int* cand_cnt = (unsigned int*)d_ws;                     // 16*CNT_STRIDE
    BParams* prm = (BParams*)(cand_cnt + NBATCH * CNT_STRIDE);        // 16 structs
    float* partials = (float*)(prm + NBATCH);                         // NB = 512
    float* tie_partials = partials + NB;                              // 16
    unsigned int* stot = (unsigned int*)(tie_partials + NBATCH);      // NB = 512
    unsigned int* cand_idx = stot + NB;                               // 16*32768
    unsigned int* cand_sb = cand_idx + NBATCH * CAND_CAP;
    float* cand_bce = (float*)(cand_sb + NBATCH * CAND_CAP);
    unsigned int* hist1 = (unsigned int*)(cand_bce + NBATCH * CAND_CAP); // 16*8192
    unsigned int* hist_part16 = hist1 + NBATCH * NBINS;               // 16*32*4096

    void* args[] = { (void*)&pred4, (void*)&mask4, (void*)&out, (void*)&cand_cnt,
                     (void*)&prm, (void*)&partials, (void*)&tie_partials,
                     (void*)&cand_idx, (void*)&cand_sb, (void*)&cand_bce,
                     (void*)&hist1, (void*)&stot, (void*)&hist_part16 };
    hipLaunchCooperativeKernel((const void*)k_all, dim3(NB), dim3(TPBC), args, 0, stream);
}

// Round 7
// 299.285 us; speedup vs baseline: 1.8872x; 1.8872x over previous
//
#include <hip/hip_runtime.h>
#include <stdint.h>

#define NBATCH 16
#define HW_ (1 << 20)            // 1024*1024 per batch
#define TPB 256

#define NBPB_H 64                // blocks per batch for hist pass (1024 blocks total)
#define TPB_H 512                // 8 waves/block, 4 blocks/CU -> 100% occupancy
#define EPB_H (HW_ / NBPB_H)     // 16384 elements per block
#define ITER_H (EPB_H / (TPB_H * 4)) // 8 float4 per thread

#define NBINS 8192               // fine bins on score_bits >> 12; base 0x3F400
#define FBASE 0x3F400

#define NSLICE 4                 // reduce slices per batch (64 blocks total)
#define SLICE_W (NBINS / 2 / NSLICE)  // 1024 packed words per slice

#define NBPB_F 256               // blocks per batch for main pass
#define FCHUNK (HW_ / NBPB_F)    // 4096 elements per block

#define CAND_CAP 32768           // ambiguous candidates per batch
#define LCAP 512                 // per-block LDS candidate capacity
#define TIE_CAP 4096
#define CNT_STRIDE 64            // u32 stride between per-batch counters (256 B)

typedef float f4v __attribute__((ext_vector_type(4)));

struct BParams {
    unsigned int k;        // n_train
    unsigned int bin1f;    // selected fine bin as raw (score_bits>>12) value; 0xFFFFFFFF if k==0
    unsigned int r;        // rank remaining within bin1f (k - count_above)
    unsigned int mode;     // 0 = no train, 1 = normal
};

__device__ __forceinline__ unsigned int score_bits(float p, int m) {
    bool correct = (p > 0.5f) == (m == 1);
    float conf = fmaxf(p, 1.0f - p);
    float base = correct ? ((conf > 0.85f) ? 1.0f : 2.0f)
                         : ((conf > 0.85f) ? 4.0f : 3.0f);
    float bonus = (conf - 0.5f) * 0.5f;   // exact in f32
    float s = correct ? (base - bonus) : (base + bonus);
    return __float_as_uint(s);            // positive floats: bit order == value order
}

__device__ __forceinline__ float agent_load_f32(const float* p) {
    return __hip_atomic_load(p, __ATOMIC_RELAXED, __HIP_MEMORY_SCOPE_AGENT);
}

// Pass 1: per-block private 8192-bin LDS histogram; 512 threads x 4 blocks/CU
// (100% wave occupancy) with a prefetch-2 software pipeline. u16-packed flush
// (counts <= 16384 fit). No global atomics.
__global__ __launch_bounds__(TPB_H, 8) void k_hist1(
        const float4* __restrict__ pred4, const int4* __restrict__ mask4,
        unsigned int* __restrict__ hist_part16) {
    __shared__ unsigned int lh[NBINS];
    int b = blockIdx.x / NBPB_H;
    int blk = blockIdx.x % NBPB_H;
    int t = threadIdx.x;
    for (int i = t; i < NBINS; i += TPB_H) lh[i] = 0;
    __syncthreads();
    size_t gb = (size_t)b * (HW_ / 4) + (size_t)blk * (EPB_H / 4);
    auto process = [&](float4 pc, int4 mc) {
        float pa[4] = {pc.x, pc.y, pc.z, pc.w};
        int ma[4] = {mc.x, mc.y, mc.z, mc.w};
#pragma unroll
        for (int l = 0; l < 4; l++) {
            if (ma[l] != 2) {
                unsigned int sb = score_bits(pa[l], ma[l]);
                int fb = (int)(sb >> 12) - FBASE;
                fb = min(max(fb, 0), NBINS - 1);
                atomicAdd(&lh[fb], 1u);
            }
        }
    };
    // prefetch-2: two named in-flight tiles (no runtime-indexed arrays)
    float4 p0 = pred4[gb + t];
    int4 m0 = mask4[gb + t];
    float4 p1 = pred4[gb + TPB_H + t];
    int4 m1 = mask4[gb + TPB_H + t];
#pragma unroll
    for (int jj = 0; jj < ITER_H; jj += 2) {
        float4 pc0 = p0; int4 mc0 = m0;
        if (jj + 2 < ITER_H) {
            p0 = pred4[gb + (size_t)(jj + 2) * TPB_H + t];
            m0 = mask4[gb + (size_t)(jj + 2) * TPB_H + t];
        }
        process(pc0, mc0);
        float4 pc1 = p1; int4 mc1 = m1;
        if (jj + 3 < ITER_H) {
            p1 = pred4[gb + (size_t)(jj + 3) * TPB_H + t];
            m1 = mask4[gb + (size_t)(jj + 3) * TPB_H + t];
        }
        process(pc1, mc1);
    }
    __syncthreads();
    // flush: pack 2 bins per u32 (u16 counts), coalesced stores
    unsigned int* hp = hist_part16 + (size_t)(b * NBPB_H + blk) * (NBINS / 2);
    for (int w = t; w < NBINS / 2; w += TPB_H)
        hp[w] = (lh[2 * w] & 0xFFFFu) | (lh[2 * w + 1] << 16);
}

// Reduce the 64 u16-packed partials into a final u32 hist. 64 blocks
// (4 slices/batch, 2048 bins each), unroll-8 over partials for MLP.
__global__ void k_reduce(const unsigned int* __restrict__ hist_part16,
                         unsigned int* __restrict__ hist1) {
    int b = blockIdx.x / NSLICE;
    int sl = blockIdx.x % NSLICE;
    int t = threadIdx.x;     // 1024
    int w = sl * SLICE_W + t;  // packed word index within batch
    unsigned int s0 = 0, s1 = 0;
#pragma unroll 8
    for (int p = 0; p < NBPB_H; p++) {
        unsigned int v = hist_part16[(size_t)(b * NBPB_H + p) * (NBINS / 2) + w];
        s0 += v & 0xFFFFu;
        s1 += v >> 16;
    }
    uint2* ob = (uint2*)(hist1 + (size_t)b * NBINS + 2 * (size_t)w);
    uint2 o = {s0, s1};
    *ob = o;
}

// Find fine bin containing the k-th largest; k derived from hist total.
// (r1-proven version; reads the 32KB final hist, L2-warm.)
__global__ void k_find1(const unsigned int* __restrict__ hist1, BParams* prm) {
    int b = blockIdx.x;
    int t = threadIdx.x;
    __shared__ unsigned int cs_[257];
    const unsigned int* h = hist1 + (size_t)b * NBINS;
    {
        const uint4* h4 = (const uint4*)(h + t * 32);
        unsigned int s = 0;
#pragma unroll
        for (int j = 0; j < 8; j++) { uint4 v = h4[j]; s += v.x + v.y + v.z + v.w; }
        cs_[t] = s;
        if (t == 0) cs_[256] = 0;
    }
    __syncthreads();
    for (int off = 1; off < 256; off <<= 1) {
        unsigned int a = (t + off < 256) ? cs_[t + off] : 0u;
        __syncthreads();
        cs_[t] += a;
        __syncthreads();
    }
    unsigned int n = cs_[0];                       // total annotated
    unsigned int k = (unsigned int)(int)((float)n * 0.5f);  // astype(f32)*0.5 -> int32
    if (k == 0) {
        if (t == 0) {
            BParams P;
            P.k = 0; P.bin1f = 0xFFFFFFFFu; P.r = 0; P.mode = 0;
            prm[b] = P;
        }
        return;
    }
    if (cs_[t] >= k && cs_[t + 1] < k) {           // unique boundary chunk
        unsigned int cum = cs_[t + 1];
        for (int j = 31; j >= 0; j--) {
            unsigned int hb = h[t * 32 + j];
            if (cum + hb >= k) {
                BParams P;
                P.k = k;
                P.bin1f = (unsigned int)(FBASE + t * 32 + j);
                P.r = k - cum;
                P.mode = 1;
                prm[b] = P;
                break;
            }
            cum += hb;
        }
    }
}

// Main fused pass (r5 control, unchanged): prefetch-1 input pipeline, in-loop
// shfl-aligned float4 stores, BCE for definite-train, LDS candidate staging.
__global__ void k_main(const float4* __restrict__ pred4, const int4* __restrict__ mask4,
                       const BParams* __restrict__ prm, float* __restrict__ out,
                       float* __restrict__ partials, unsigned int* __restrict__ cand_cnt,
                       unsigned int* __restrict__ cand_idx, unsigned int* __restrict__ cand_sb,
                       float* __restrict__ cand_bce) {
    int b = blockIdx.x / NBPB_F;
    int blk = blockIdx.x % NBPB_F;
    BParams P = prm[b];
    unsigned int target = P.bin1f;
    __shared__ unsigned int lcode[FCHUNK / 4];   // code word per input quad
    __shared__ float red[TPB];
    __shared__ unsigned int l_idx[LCAP];
    __shared__ unsigned int l_sb[LCAP];
    __shared__ float l_bce[LCAP];
    __shared__ unsigned int lcnt;
    __shared__ unsigned int gbase;
    if (threadIdx.x == 0) lcnt = 0;
    __syncthreads();
    float acc = 0.0f;
    int ibase = blk * FCHUNK;
    size_t base4 = (size_t)b * (HW_ / 4) + (size_t)(ibase / 4);
    float* trout = out + 1;
    float* hoout = out + 1 + (size_t)NBATCH * HW_;
    size_t Gbase = (size_t)b * HW_ + (size_t)ibase;
    int lane = threadIdx.x & 63;
    float4 p = pred4[base4 + threadIdx.x];
    int4 m = mask4[base4 + threadIdx.x];
#pragma unroll
    for (int j = 0; j < FCHUNK / (TPB * 4); j++) {   // 4 iterations
        int v = j * TPB + threadIdx.x;               // word index [0,1024)
        float4 pc = p;
        int4 mc = m;
        if (j + 1 < FCHUNK / (TPB * 4)) {
            p = pred4[base4 + (size_t)(j + 1) * TPB + threadIdx.x];
            m = mask4[base4 + (size_t)(j + 1) * TPB + threadIdx.x];
        }
        float pa[4] = {pc.x, pc.y, pc.z, pc.w};
        int ma[4] = {mc.x, mc.y, mc.z, mc.w};
        unsigned int cw = 0;
#pragma unroll
        for (int l = 0; l < 4; l++) {
            bool ann = (ma[l] != 2);
            unsigned int sb = score_bits(pa[l], ma[l]);
            unsigned int fine = sb >> 12;
            bool tr = ann && (fine > target);
            bool amb = ann && (fine == target);
            unsigned int code = (tr ? 1u : 0u) | ((ann && !tr) ? 2u : 0u);
            cw |= code << (8 * l);
            float bce = 0.0f;
            if (tr || amb) {
                float pc2 = fminf(fmaxf(pa[l], 1e-7f), 1.0f - 1e-7f);
                bce = (ma[l] == 1) ? -__logf(pc2) : -__logf(1.0f - pc2);
            }
            if (tr) acc += bce;
            if (amb) {
                unsigned int p0 = atomicAdd(&lcnt, 1u);  // LDS atomic
                if (p0 < LCAP) {
                    l_idx[p0] = (unsigned int)(ibase + v * 4 + l);
                    l_sb[p0] = sb;
                    l_bce[p0] = bce;
                } else {
                    unsigned int gp = atomicAdd(&cand_cnt[b * CNT_STRIDE], 1u);
                    if (gp < CAND_CAP) {
                        size_t o = (size_t)b * CAND_CAP + gp;
                        cand_idx[o] = (unsigned int)(ibase + v * 4 + l);
                        cand_sb[o] = sb;
                        cand_bce[o] = bce;
                    }
                }
            }
        }
        lcode[v] = cw;   // stride-1 ds_write_b32 (boundary/head/tail fixups)
        unsigned int nw = (unsigned int)__shfl_down((int)cw, 1);
        if (lane != 63) {
            unsigned int c0 = cw >> 24;
            unsigned int c1 = nw & 0xFFu;
            unsigned int c2 = (nw >> 8) & 0xFFu;
            unsigned int c3 = (nw >> 16) & 0xFFu;
            int e = 3 + 4 * v;
            f4v tv = { (float)(c0 & 1u), (float)(c1 & 1u), (float)(c2 & 1u), (float)(c3 & 1u) };
            f4v hv = { (float)((c0 >> 1) & 1u), (float)((c1 >> 1) & 1u),
                       (float)((c2 >> 1) & 1u), (float)((c3 >> 1) & 1u) };
            *(f4v*)(trout + Gbase + e) = tv;
            *(f4v*)(hoout + Gbase + e) = hv;
        }
    }
    __syncthreads();
    unsigned int n = min(lcnt, (unsigned int)LCAP);
    if (threadIdx.x == 0 && n > 0)
        gbase = atomicAdd(&cand_cnt[b * CNT_STRIDE], n);
    __syncthreads();
    for (unsigned int i = threadIdx.x; i < n; i += TPB) {
        unsigned int pos = gbase + i;
        if (pos < CAND_CAP) {
            size_t o = (size_t)b * CAND_CAP + pos;
            cand_idx[o] = l_idx[i];
            cand_sb[o] = l_sb[i];
            cand_bce[o] = l_bce[i];
        }
    }
    // wave-boundary fixups: words v = j*TPB + w*64 + 63 (skipped in-loop), except 1023
    if (threadIdx.x < 16) {
        int j = threadIdx.x >> 2, w = threadIdx.x & 3;
        int v = j * TPB + w * 64 + 63;
        if (v < FCHUNK / 4 - 1) {
            unsigned int w0 = lcode[v];
            unsigned int w1 = lcode[v + 1];
            unsigned int c0 = w0 >> 24;
            unsigned int c1 = w1 & 0xFFu;
            unsigned int c2 = (w1 >> 8) & 0xFFu;
            unsigned int c3 = (w1 >> 16) & 0xFFu;
            int e = 3 + 4 * v;
            f4v tv = { (float)(c0 & 1u), (float)(c1 & 1u), (float)(c2 & 1u), (float)(c3 & 1u) };
            f4v hv = { (float)((c0 >> 1) & 1u), (float)((c1 >> 1) & 1u),
                       (float)((c2 >> 1) & 1u), (float)((c3 >> 1) & 1u) };
            *(f4v*)(trout + Gbase + e) = tv;
            *(f4v*)(hoout + Gbase + e) = hv;
        }
    }
    if (threadIdx.x >= 16 && threadIdx.x < 19) {   // head elems 0,1,2
        int i = threadIdx.x - 16;
        unsigned int c = (lcode[0] >> (8 * i)) & 0xFFu;
        trout[Gbase + i] = (float)(c & 1u);
        hoout[Gbase + i] = (float)((c >> 1) & 1u);
    }
    if (threadIdx.x == 19) {  // tail elem 4095
        unsigned int c = (lcode[FCHUNK / 4 - 1] >> 24) & 0xFFu;
        trout[Gbase + FCHUNK - 1] = (float)(c & 1u);
        hoout[Gbase + FCHUNK - 1] = (float)((c >> 1) & 1u);
    }
    red[threadIdx.x] = acc;
    __syncthreads();
    for (int off = TPB / 2; off > 0; off >>= 1) {
        if (threadIdx.x < off) red[threadIdx.x] += red[threadIdx.x + off];
        __syncthreads();
    }
    if (threadIdx.x == 0) partials[blockIdx.x] = red[0];
}

// Fixup (fused with loss, r5 control): exact low-12-bit select, tie-break on index,
// scatter-correct masks, tie BCE; last block (done-counter) computes the loss.
__global__ void k_fixup(const unsigned int* __restrict__ cand_cnt,
                        const unsigned int* __restrict__ cand_idx,
                        const unsigned int* __restrict__ cand_sb,
                        const float* __restrict__ cand_bce,
                        const BParams* __restrict__ prm, float* __restrict__ out,
                        float* __restrict__ tie_partials,
                        const float* __restrict__ partials,
                        unsigned int* __restrict__ done_f) {
    int b = blockIdx.x;
    int t = threadIdx.x;
    __shared__ unsigned int h[4096];
    __shared__ unsigned int cs_[257];
    __shared__ unsigned int tie_idx[TIE_CAP];
    __shared__ unsigned int misc[8];
    __shared__ float red[TPB];
    __shared__ double redd[TPB];
    __shared__ unsigned int lastf;
    BParams P = prm[b];
    float tieval = 0.0f;
    if (P.mode != 0) {
        unsigned int C = cand_cnt[b * CNT_STRIDE];
        if (C > CAND_CAP) C = CAND_CAP;
        const unsigned int* ci = cand_idx + (size_t)b * CAND_CAP;
        const unsigned int* cs = cand_sb + (size_t)b * CAND_CAP;
        const float* cb = cand_bce + (size_t)b * CAND_CAP;
        for (int i = t; i < 4096; i += TPB) h[i] = 0;
        if (t < 8) misc[t] = (t == 4) ? 0xFFFFFFFFu : 0u;
        __syncthreads();
        for (unsigned int i = t; i < C; i += TPB)
            atomicAdd(&h[cs[i] & 0xFFFu], 1u);
        __syncthreads();
        {
            unsigned int gs = 0;
#pragma unroll
            for (int j = 0; j < 16; j++) gs += h[t * 16 + j];
            cs_[t] = gs;
            if (t == 0) cs_[256] = 0;
        }
        __syncthreads();
        for (int off = 1; off < 256; off <<= 1) {
            unsigned int a = (t + off < 256) ? cs_[t + off] : 0u;
            __syncthreads();
            cs_[t] += a;
            __syncthreads();
        }
        if (cs_[t] >= P.r && cs_[t + 1] < P.r) {
            unsigned int cum = cs_[t + 1];
            for (int j = 15; j >= 0; j--) {
                unsigned int hb = h[t * 16 + j];
                if (cum + hb >= P.r) {
                    unsigned int T = P.r - cum;
                    misc[0] = (unsigned int)(t * 16 + j);
                    misc[1] = T;
                    misc[2] = (T == hb) ? 1u : 0u;
                    break;
                }
                cum += hb;
            }
        }
        __syncthreads();
        unsigned int vstar = misc[0], T = misc[1];
        bool allTies = (misc[2] != 0);
        unsigned int idxcut;
        if (allTies) {
            idxcut = 0xFFFFFFFFu;
        } else {
            for (unsigned int i = t; i < C; i += TPB) {
                if ((cs[i] & 0xFFFu) == vstar) {
                    unsigned int p = atomicAdd(&misc[3], 1u);
                    if (p < TIE_CAP) tie_idx[p] = ci[i];
                }
            }
            __syncthreads();
            unsigned int E2 = misc[3];
            if (E2 > TIE_CAP) E2 = TIE_CAP;
            for (unsigned int i = t; i < E2; i += TPB) {
                unsigned int vi = tie_idx[i];
                unsigned int cnt = 0;
                for (unsigned int j = 0; j < E2; j++) cnt += (tie_idx[j] < vi) ? 1u : 0u;
                if (cnt == T - 1) misc[4] = vi;
            }
            __syncthreads();
            idxcut = misc[4];
        }
        float acc = 0.0f;
        float* trout = out + 1;
        float* hoout = out + 1 + (size_t)NBATCH * HW_;
        size_t base = (size_t)b * HW_;
        for (unsigned int i = t; i < C; i += TPB) {
            unsigned int low = cs[i] & 0xFFFu;
            bool tr = (low > vstar) || (low == vstar && ci[i] <= idxcut);
            if (tr) {
                trout[base + ci[i]] = 1.0f;
                hoout[base + ci[i]] = 0.0f;
                acc += cb[i];
            }
        }
        red[t] = acc;
        __syncthreads();
        for (int off = TPB / 2; off > 0; off >>= 1) {
            if (t < off) red[t] += red[t + off];
            __syncthreads();
        }
        if (t == 0) tieval = red[0];
    }
    if (t == 0)
        __hip_atomic_store(&tie_partials[b], tieval, __ATOMIC_RELAXED, __HIP_MEMORY_SCOPE_AGENT);
    __threadfence();
    __syncthreads();
    if (t == 0) lastf = (atomicAdd(done_f, 1u) == (unsigned int)(NBATCH - 1)) ? 1u : 0u;
    __syncthreads();
    if (!lastf) return;
    __threadfence();
    double s = 0.0;
    for (int i = t; i < NBATCH * NBPB_F; i += TPB) s += (double)partials[i];
    if (t < NBATCH) s += (double)agent_load_f32(&tie_partials[t]);
    redd[t] = s;
    __syncthreads();
    for (int off = TPB / 2; off > 0; off >>= 1) {
        if (t < off) redd[t] += redd[t + off];
        __syncthreads();
    }
    if (t == 0) {
        unsigned long long den = 0;
        for (int b2 = 0; b2 < NBATCH; b2++) den += prm[b2].k;
        float denf = (float)den + 1e-7f;
        out[0] = (float)redd[0] / denf;
    }
}

extern "C" void kernel_launch(void* const* d_in, const int* in_sizes, int n_in,
                              void* d_out, int out_size, void* d_ws, size_t ws_size,
                              hipStream_t stream) {
    const float4* pred4 = (const float4*)d_in[0];
    const int4* mask4 = (const int4*)d_in[1];
    float* out = (float*)d_out;

    // workspace layout (u32 words): zeroed region (cand_cnt + done) first.
    unsigned int* cand_cnt = (unsigned int*)d_ws;                     // 16*CNT_STRIDE
    unsigned int* done_f = cand_cnt + NBATCH * CNT_STRIDE;            // 32 (only [0] used)
    BParams* prm = (BParams*)(done_f + 32);                           // 16 structs
    float* partials = (float*)(prm + NBATCH);                         // 16*256
    float* tie_partials = partials + NBATCH * NBPB_F;                 // 16
    unsigned int* cand_idx = (unsigned int*)(tie_partials + NBATCH);  // 16*32768
    unsigned int* cand_sb = cand_idx + NBATCH * CAND_CAP;
    float* cand_bce = (float*)(cand_sb + NBATCH * CAND_CAP);
    unsigned int* hist1 = (unsigned int*)(cand_bce + NBATCH * CAND_CAP); // 16*8192
    unsigned int* hist_part16 = hist1 + NBATCH * NBINS;               // 1024*4096

    size_t zero_bytes = (size_t)(NBATCH * CNT_STRIDE + 32) * 4;
    hipMemsetAsync(d_ws, 0, zero_bytes, stream);

    k_hist1<<<dim3(NBATCH * NBPB_H), dim3(TPB_H), 0, stream>>>(pred4, mask4, hist_part16);
    k_reduce<<<dim3(NBATCH * NSLICE), dim3(1024), 0, stream>>>(hist_part16, hist1);
    k_find1<<<dim3(NBATCH), dim3(TPB), 0, stream>>>(hist1, prm);
    k_main<<<dim3(NBATCH * NBPB_F), dim3(TPB), 0, stream>>>(pred4, mask4, prm, out, partials,
                                                            cand_cnt, cand_idx, cand_sb, cand_bce);
    k_fixup<<<dim3(NBATCH), dim3(TPB), 0, stream>>>(cand_cnt, cand_idx, cand_sb, cand_bce,
                                                    prm, out, tie_partials, partials, done_f);
}

// Round 8
// 294.502 us; speedup vs baseline: 1.9179x; 1.0162x over previous
//
#include <hip/hip_runtime.h>
#include <stdint.h>

#define NBATCH 16
#define HW_ (1 << 20)            // 1024*1024 per batch
#define TPB 256

// --- instrumentation grid: heavies sized to exceed the ~82us fill cutoff ---
#define NBPB_H 16                // blocks per batch for hist pass (256 total, 1/CU)
#define TPB_H 512
#define EPB_H (HW_ / NBPB_H)     // 65536 elements per block
#define ITER_H (EPB_H / (TPB_H * 4)) // 32 float4 per thread

#define NBINS 8192               // fine bins on score_bits >> 12; base 0x3F400
#define FBASE 0x3F400

#define NSLICE 4                 // reduce slices per batch (64 blocks total)
#define SLICE_BINS (NBINS / NSLICE)  // 2048 bins per slice

#define NBPB_F 64                // blocks per batch for main pass (1024 total)
#define FCHUNK (HW_ / NBPB_F)    // 16384 elements per block

#define CAND_CAP 32768           // ambiguous candidates per batch
#define LCAP 512                 // per-block LDS candidate capacity
#define TIE_CAP 4096
#define CNT_STRIDE 64            // u32 stride between per-batch counters (256 B)

typedef float f4v __attribute__((ext_vector_type(4)));

struct BParams {
    unsigned int k;        // n_train
    unsigned int bin1f;    // selected fine bin as raw (score_bits>>12) value; 0xFFFFFFFF if k==0
    unsigned int r;        // rank remaining within bin1f (k - count_above)
    unsigned int mode;     // 0 = no train, 1 = normal
};

__device__ __forceinline__ unsigned int score_bits(float p, int m) {
    bool correct = (p > 0.5f) == (m == 1);
    float conf = fmaxf(p, 1.0f - p);
    float base = correct ? ((conf > 0.85f) ? 1.0f : 2.0f)
                         : ((conf > 0.85f) ? 4.0f : 3.0f);
    float bonus = (conf - 0.5f) * 0.5f;   // exact in f32
    float s = correct ? (base - bonus) : (base + bonus);
    return __float_as_uint(s);            // positive floats: bit order == value order
}

__device__ __forceinline__ float agent_load_f32(const float* p) {
    return __hip_atomic_load(p, __ATOMIC_RELAXED, __HIP_MEMORY_SCOPE_AGENT);
}

// Pass 1: per-block private 8192-bin LDS histogram; prefetch-2 pipeline; u32 flush.
// Inner loop IDENTICAL to r7 (so counters transfer); only the grid is smaller.
__global__ __launch_bounds__(TPB_H, 8) void k_hist1(
        const float4* __restrict__ pred4, const int4* __restrict__ mask4,
        unsigned int* __restrict__ hist_part) {
    __shared__ unsigned int lh[NBINS];
    int b = blockIdx.x / NBPB_H;
    int blk = blockIdx.x % NBPB_H;
    int t = threadIdx.x;
    for (int i = t; i < NBINS; i += TPB_H) lh[i] = 0;
    __syncthreads();
    size_t gb = (size_t)b * (HW_ / 4) + (size_t)blk * (EPB_H / 4);
    auto process = [&](float4 pc, int4 mc) {
        float pa[4] = {pc.x, pc.y, pc.z, pc.w};
        int ma[4] = {mc.x, mc.y, mc.z, mc.w};
#pragma unroll
        for (int l = 0; l < 4; l++) {
            if (ma[l] != 2) {
                unsigned int sb = score_bits(pa[l], ma[l]);
                int fb = (int)(sb >> 12) - FBASE;
                fb = min(max(fb, 0), NBINS - 1);
                atomicAdd(&lh[fb], 1u);
            }
        }
    };
    float4 p0 = pred4[gb + t];
    int4 m0 = mask4[gb + t];
    float4 p1 = pred4[gb + TPB_H + t];
    int4 m1 = mask4[gb + TPB_H + t];
    for (int jj = 0; jj < ITER_H; jj += 2) {
        float4 pc0 = p0; int4 mc0 = m0;
        if (jj + 2 < ITER_H) {
            p0 = pred4[gb + (size_t)(jj + 2) * TPB_H + t];
            m0 = mask4[gb + (size_t)(jj + 2) * TPB_H + t];
        }
        process(pc0, mc0);
        float4 pc1 = p1; int4 mc1 = m1;
        if (jj + 3 < ITER_H) {
            p1 = pred4[gb + (size_t)(jj + 3) * TPB_H + t];
            m1 = mask4[gb + (size_t)(jj + 3) * TPB_H + t];
        }
        process(pc1, mc1);
    }
    __syncthreads();
    unsigned int* hp = hist_part + (size_t)(b * NBPB_H + blk) * NBINS;
    for (int i = t; i < NBINS; i += TPB_H) hp[i] = lh[i];
}

// Reduce the 16 u32 partials into a final hist. 64 blocks (4 slices/batch).
__global__ void k_reduce(const unsigned int* __restrict__ hist_part,
                         unsigned int* __restrict__ hist1) {
    int b = blockIdx.x / NSLICE;
    int sl = blockIdx.x % NSLICE;
    int t = threadIdx.x;     // 1024
    for (int r = 0; r < SLICE_BINS; r += 1024) {
        int bin = sl * SLICE_BINS + r + t;
        unsigned int s = 0;
#pragma unroll
        for (int p = 0; p < NBPB_H; p++)
            s += hist_part[(size_t)(b * NBPB_H + p) * NBINS + bin];
        hist1[(size_t)b * NBINS + bin] = s;
    }
}

// Find fine bin containing the k-th largest (r1-proven, unchanged).
__global__ void k_find1(const unsigned int* __restrict__ hist1, BParams* prm) {
    int b = blockIdx.x;
    int t = threadIdx.x;
    __shared__ unsigned int cs_[257];
    const unsigned int* h = hist1 + (size_t)b * NBINS;
    {
        const uint4* h4 = (const uint4*)(h + t * 32);
        unsigned int s = 0;
#pragma unroll
        for (int j = 0; j < 8; j++) { uint4 v = h4[j]; s += v.x + v.y + v.z + v.w; }
        cs_[t] = s;
        if (t == 0) cs_[256] = 0;
    }
    __syncthreads();
    for (int off = 1; off < 256; off <<= 1) {
        unsigned int a = (t + off < 256) ? cs_[t + off] : 0u;
        __syncthreads();
        cs_[t] += a;
        __syncthreads();
    }
    unsigned int n = cs_[0];
    unsigned int k = (unsigned int)(int)((float)n * 0.5f);  // astype(f32)*0.5 -> int32
    if (k == 0) {
        if (t == 0) {
            BParams P;
            P.k = 0; P.bin1f = 0xFFFFFFFFu; P.r = 0; P.mode = 0;
            prm[b] = P;
        }
        return;
    }
    if (cs_[t] >= k && cs_[t + 1] < k) {
        unsigned int cum = cs_[t + 1];
        for (int j = 31; j >= 0; j--) {
            unsigned int hb = h[t * 32 + j];
            if (cum + hb >= k) {
                BParams P;
                P.k = k;
                P.bin1f = (unsigned int)(FBASE + t * 32 + j);
                P.r = k - cum;
                P.mode = 1;
                prm[b] = P;
                break;
            }
            cum += hb;
        }
    }
}

// Main fused pass: inner loop IDENTICAL to r7; only FCHUNK larger (16384).
__global__ void k_main(const float4* __restrict__ pred4, const int4* __restrict__ mask4,
                       const BParams* __restrict__ prm, float* __restrict__ out,
                       float* __restrict__ partials, unsigned int* __restrict__ cand_cnt,
                       unsigned int* __restrict__ cand_idx, unsigned int* __restrict__ cand_sb,
                       float* __restrict__ cand_bce) {
    int b = blockIdx.x / NBPB_F;
    int blk = blockIdx.x % NBPB_F;
    BParams P = prm[b];
    unsigned int target = P.bin1f;
    __shared__ unsigned int lcode[FCHUNK / 4];   // 16 KB
    __shared__ float red[TPB];
    __shared__ unsigned int l_idx[LCAP];
    __shared__ unsigned int l_sb[LCAP];
    __shared__ float l_bce[LCAP];
    __shared__ unsigned int lcnt;
    __shared__ unsigned int gbase;
    if (threadIdx.x == 0) lcnt = 0;
    __syncthreads();
    float acc = 0.0f;
    int ibase = blk * FCHUNK;
    size_t base4 = (size_t)b * (HW_ / 4) + (size_t)(ibase / 4);
    float* trout = out + 1;
    float* hoout = out + 1 + (size_t)NBATCH * HW_;
    size_t Gbase = (size_t)b * HW_ + (size_t)ibase;
    int lane = threadIdx.x & 63;
    float4 p = pred4[base4 + threadIdx.x];
    int4 m = mask4[base4 + threadIdx.x];
    for (int j = 0; j < FCHUNK / (TPB * 4); j++) {   // 16 iterations
        int v = j * TPB + threadIdx.x;               // word index [0,4096)
        float4 pc = p;
        int4 mc = m;
        if (j + 1 < FCHUNK / (TPB * 4)) {
            p = pred4[base4 + (size_t)(j + 1) * TPB + threadIdx.x];
            m = mask4[base4 + (size_t)(j + 1) * TPB + threadIdx.x];
        }
        float pa[4] = {pc.x, pc.y, pc.z, pc.w};
        int ma[4] = {mc.x, mc.y, mc.z, mc.w};
        unsigned int cw = 0;
#pragma unroll
        for (int l = 0; l < 4; l++) {
            bool ann = (ma[l] != 2);
            unsigned int sb = score_bits(pa[l], ma[l]);
            unsigned int fine = sb >> 12;
            bool tr = ann && (fine > target);
            bool amb = ann && (fine == target);
            unsigned int code = (tr ? 1u : 0u) | ((ann && !tr) ? 2u : 0u);
            cw |= code << (8 * l);
            float bce = 0.0f;
            if (tr || amb) {
                float pc2 = fminf(fmaxf(pa[l], 1e-7f), 1.0f - 1e-7f);
                bce = (ma[l] == 1) ? -__logf(pc2) : -__logf(1.0f - pc2);
            }
            if (tr) acc += bce;
            if (amb) {
                unsigned int p0 = atomicAdd(&lcnt, 1u);  // LDS atomic
                if (p0 < LCAP) {
                    l_idx[p0] = (unsigned int)(ibase + v * 4 + l);
                    l_sb[p0] = sb;
                    l_bce[p0] = bce;
                } else {
                    unsigned int gp = atomicAdd(&cand_cnt[b * CNT_STRIDE], 1u);
                    if (gp < CAND_CAP) {
                        size_t o = (size_t)b * CAND_CAP + gp;
                        cand_idx[o] = (unsigned int)(ibase + v * 4 + l);
                        cand_sb[o] = sb;
                        cand_bce[o] = bce;
                    }
                }
            }
        }
        lcode[v] = cw;
        unsigned int nw = (unsigned int)__shfl_down((int)cw, 1);
        if (lane != 63) {
            unsigned int c0 = cw >> 24;
            unsigned int c1 = nw & 0xFFu;
            unsigned int c2 = (nw >> 8) & 0xFFu;
            unsigned int c3 = (nw >> 16) & 0xFFu;
            int e = 3 + 4 * v;
            f4v tv = { (float)(c0 & 1u), (float)(c1 & 1u), (float)(c2 & 1u), (float)(c3 & 1u) };
            f4v hv = { (float)((c0 >> 1) & 1u), (float)((c1 >> 1) & 1u),
                       (float)((c2 >> 1) & 1u), (float)((c3 >> 1) & 1u) };
            *(f4v*)(trout + Gbase + e) = tv;
            *(f4v*)(hoout + Gbase + e) = hv;
        }
    }
    __syncthreads();
    unsigned int n = min(lcnt, (unsigned int)LCAP);
    if (threadIdx.x == 0 && n > 0)
        gbase = atomicAdd(&cand_cnt[b * CNT_STRIDE], n);
    __syncthreads();
    for (unsigned int i = threadIdx.x; i < n; i += TPB) {
        unsigned int pos = gbase + i;
        if (pos < CAND_CAP) {
            size_t o = (size_t)b * CAND_CAP + pos;
            cand_idx[o] = l_idx[i];
            cand_sb[o] = l_sb[i];
            cand_bce[o] = l_bce[i];
        }
    }
    // wave-boundary fixups: words v = j*TPB + w*64 + 63 (64 of them), except 4095
    if (threadIdx.x < 64) {
        int j = threadIdx.x >> 2, w = threadIdx.x & 3;
        int v = j * TPB + w * 64 + 63;
        if (v < FCHUNK / 4 - 1) {
            unsigned int w0 = lcode[v];
            unsigned int w1 = lcode[v + 1];
            unsigned int c0 = w0 >> 24;
            unsigned int c1 = w1 & 0xFFu;
            unsigned int c2 = (w1 >> 8) & 0xFFu;
            unsigned int c3 = (w1 >> 16) & 0xFFu;
            int e = 3 + 4 * v;
            f4v tv = { (float)(c0 & 1u), (float)(c1 & 1u), (float)(c2 & 1u), (float)(c3 & 1u) };
            f4v hv = { (float)((c0 >> 1) & 1u), (float)((c1 >> 1) & 1u),
                       (float)((c2 >> 1) & 1u), (float)((c3 >> 1) & 1u) };
            *(f4v*)(trout + Gbase + e) = tv;
            *(f4v*)(hoout + Gbase + e) = hv;
        }
    }
    if (threadIdx.x >= 64 && threadIdx.x < 67) {   // head elems 0,1,2
        int i = threadIdx.x - 64;
        unsigned int c = (lcode[0] >> (8 * i)) & 0xFFu;
        trout[Gbase + i] = (float)(c & 1u);
        hoout[Gbase + i] = (float)((c >> 1) & 1u);
    }
    if (threadIdx.x == 67) {  // tail elem FCHUNK-1
        unsigned int c = (lcode[FCHUNK / 4 - 1] >> 24) & 0xFFu;
        trout[Gbase + FCHUNK - 1] = (float)(c & 1u);
        hoout[Gbase + FCHUNK - 1] = (float)((c >> 1) & 1u);
    }
    red[threadIdx.x] = acc;
    __syncthreads();
    for (int off = TPB / 2; off > 0; off >>= 1) {
        if (threadIdx.x < off) red[threadIdx.x] += red[threadIdx.x + off];
        __syncthreads();
    }
    if (threadIdx.x == 0) partials[blockIdx.x] = red[0];
}

// Fixup (fused with loss): unchanged from r7 (loop bounds follow macros).
__global__ void k_fixup(const unsigned int* __restrict__ cand_cnt,
                        const unsigned int* __restrict__ cand_idx,
                        const unsigned int* __restrict__ cand_sb,
                        const float* __restrict__ cand_bce,
                        const BParams* __restrict__ prm, float* __restrict__ out,
                        float* __restrict__ tie_partials,
                        const float* __restrict__ partials,
                        unsigned int* __restrict__ done_f) {
    int b = blockIdx.x;
    int t = threadIdx.x;
    __shared__ unsigned int h[4096];
    __shared__ unsigned int cs_[257];
    __shared__ unsigned int tie_idx[TIE_CAP];
    __shared__ unsigned int misc[8];
    __shared__ float red[TPB];
    __shared__ double redd[TPB];
    __shared__ unsigned int lastf;
    BParams P = prm[b];
    float tieval = 0.0f;
    if (P.mode != 0) {
        unsigned int C = cand_cnt[b * CNT_STRIDE];
        if (C > CAND_CAP) C = CAND_CAP;
        const unsigned int* ci = cand_idx + (size_t)b * CAND_CAP;
        const unsigned int* cs = cand_sb + (size_t)b * CAND_CAP;
        const float* cb = cand_bce + (size_t)b * CAND_CAP;
        for (int i = t; i < 4096; i += TPB) h[i] = 0;
        if (t < 8) misc[t] = (t == 4) ? 0xFFFFFFFFu : 0u;
        __syncthreads();
        for (unsigned int i = t; i < C; i += TPB)
            atomicAdd(&h[cs[i] & 0xFFFu], 1u);
        __syncthreads();
        {
            unsigned int gs = 0;
#pragma unroll
            for (int j = 0; j < 16; j++) gs += h[t * 16 + j];
            cs_[t] = gs;
            if (t == 0) cs_[256] = 0;
        }
        __syncthreads();
        for (int off = 1; off < 256; off <<= 1) {
            unsigned int a = (t + off < 256) ? cs_[t + off] : 0u;
            __syncthreads();
            cs_[t] += a;
            __syncthreads();
        }
        if (cs_[t] >= P.r && cs_[t + 1] < P.r) {
            unsigned int cum = cs_[t + 1];
            for (int j = 15; j >= 0; j--) {
                unsigned int hb = h[t * 16 + j];
                if (cum + hb >= P.r) {
                    unsigned int T = P.r - cum;
                    misc[0] = (unsigned int)(t * 16 + j);
                    misc[1] = T;
                    misc[2] = (T == hb) ? 1u : 0u;
                    break;
                }
                cum += hb;
            }
        }
        __syncthreads();
        unsigned int vstar = misc[0], T = misc[1];
        bool allTies = (misc[2] != 0);
        unsigned int idxcut;
        if (allTies) {
            idxcut = 0xFFFFFFFFu;
        } else {
            for (unsigned int i = t; i < C; i += TPB) {
                if ((cs[i] & 0xFFFu) == vstar) {
                    unsigned int p = atomicAdd(&misc[3], 1u);
                    if (p < TIE_CAP) tie_idx[p] = ci[i];
                }
            }
            __syncthreads();
            unsigned int E2 = misc[3];
            if (E2 > TIE_CAP) E2 = TIE_CAP;
            for (unsigned int i = t; i < E2; i += TPB) {
                unsigned int vi = tie_idx[i];
                unsigned int cnt = 0;
                for (unsigned int j = 0; j < E2; j++) cnt += (tie_idx[j] < vi) ? 1u : 0u;
                if (cnt == T - 1) misc[4] = vi;
            }
            __syncthreads();
            idxcut = misc[4];
        }
        float acc = 0.0f;
        float* trout = out + 1;
        float* hoout = out + 1 + (size_t)NBATCH * HW_;
        size_t base = (size_t)b * HW_;
        for (unsigned int i = t; i < C; i += TPB) {
            unsigned int low = cs[i] & 0xFFFu;
            bool tr = (low > vstar) || (low == vstar && ci[i] <= idxcut);
            if (tr) {
                trout[base + ci[i]] = 1.0f;
                hoout[base + ci[i]] = 0.0f;
                acc += cb[i];
            }
        }
        red[t] = acc;
        __syncthreads();
        for (int off = TPB / 2; off > 0; off >>= 1) {
            if (t < off) red[t] += red[t + off];
            __syncthreads();
        }
        if (t == 0) tieval = red[0];
    }
    if (t == 0)
        __hip_atomic_store(&tie_partials[b], tieval, __ATOMIC_RELAXED, __HIP_MEMORY_SCOPE_AGENT);
    __threadfence();
    __syncthreads();
    if (t == 0) lastf = (atomicAdd(done_f, 1u) == (unsigned int)(NBATCH - 1)) ? 1u : 0u;
    __syncthreads();
    if (!lastf) return;
    __threadfence();
    double s = 0.0;
    for (int i = t; i < NBATCH * NBPB_F; i += TPB) s += (double)partials[i];
    if (t < NBATCH) s += (double)agent_load_f32(&tie_partials[t]);
    redd[t] = s;
    __syncthreads();
    for (int off = TPB / 2; off > 0; off >>= 1) {
        if (t < off) redd[t] += redd[t + off];
        __syncthreads();
    }
    if (t == 0) {
        unsigned long long den = 0;
        for (int b2 = 0; b2 < NBATCH; b2++) den += prm[b2].k;
        float denf = (float)den + 1e-7f;
        out[0] = (float)redd[0] / denf;
    }
}

extern "C" void kernel_launch(void* const* d_in, const int* in_sizes, int n_in,
                              void* d_out, int out_size, void* d_ws, size_t ws_size,
                              hipStream_t stream) {
    const float4* pred4 = (const float4*)d_in[0];
    const int4* mask4 = (const int4*)d_in[1];
    float* out = (float*)d_out;

    unsigned int* cand_cnt = (unsigned int*)d_ws;                     // 16*CNT_STRIDE
    unsigned int* done_f = cand_cnt + NBATCH * CNT_STRIDE;            // 32 (only [0] used)
    BParams* prm = (BParams*)(done_f + 32);                           // 16 structs
    float* partials = (float*)(prm + NBATCH);                         // 16*NBPB_F
    float* tie_partials = partials + NBATCH * NBPB_F;                 // 16
    unsigned int* cand_idx = (unsigned int*)(tie_partials + NBATCH);  // 16*32768
    unsigned int* cand_sb = cand_idx + NBATCH * CAND_CAP;
    float* cand_bce = (float*)(cand_sb + NBATCH * CAND_CAP);
    unsigned int* hist1 = (unsigned int*)(cand_bce + NBATCH * CAND_CAP); // 16*8192
    unsigned int* hist_part = hist1 + NBATCH * NBINS;                 // 256*8192 u32 (8 MB)

    size_t zero_bytes = (size_t)(NBATCH * CNT_STRIDE + 32) * 4;
    hipMemsetAsync(d_ws, 0, zero_bytes, stream);

    k_hist1<<<dim3(NBATCH * NBPB_H), dim3(TPB_H), 0, stream>>>(pred4, mask4, hist_part);
    k_reduce<<<dim3(NBATCH * NSLICE), dim3(1024), 0, stream>>>(hist_part, hist1);
    k_find1<<<dim3(NBATCH), dim3(TPB), 0, stream>>>(hist1, prm);
    k_main<<<dim3(NBATCH * NBPB_F), dim3(TPB), 0, stream>>>(pred4, mask4, prm, out, partials,
                                                            cand_cnt, cand_idx, cand_sb, cand_bce);
    k_fixup<<<dim3(NBATCH), dim3(TPB), 0, stream>>>(cand_cnt, cand_idx, cand_sb, cand_bce,
                                                    prm, out, tie_partials, partials, done_f);
}